// Round 6
// baseline (227.549 us; speedup 1.0000x reference)
//
#include <hip/hip_runtime.h>
#include <math.h>

// out[b] = log( sum_kk (w[kk>>8]*W0[kk,x0[b]]) * W1[kk,x1[b]] ),  kk in [0,65536)
//
// gemm: 512 blocks x 256 threads (4 waves), TWO blocks per CU (the round-6
// change: two independent barrier domains per CU so one block streams while
// the other waits -- breaks the 1-block lockstep that capped us at ~1.8 TB/s).
// Block = (split = one latent k, 256 kk rows) x (h = c0 half): tile 128x256.
// W0 read once; W1 read by both h-blocks of a split (pair-mates mapped to the
// same XCD via blk^8 so the second read L2-hits). w_sum folded into epilogue.
// BK=32, register prefetch of iter+1, swizzled 64B-row LDS (2-way max).
// Epilogue: 4-phase LDS dump + gather of the 1024 observed pairs -> plain
// coalesced stores to P[512][1024]; finish reduces + log.

#define KCHUNK  256
#define BK      32
#define NITER   (KCHUNK / BK)   // 8

typedef float  f32x4  __attribute__((ext_vector_type(4)));
typedef short  bf16x8 __attribute__((ext_vector_type(8)));

static __device__ __forceinline__ short f2bf(float f) {
    // RNE fp32 -> bf16 (positive probabilities; no NaN/Inf)
    unsigned u = __builtin_bit_cast(unsigned, f);
    u += 0x7fffu + ((u >> 16) & 1u);
    return (short)(u >> 16);
}

// LDS row = 32 bf16 = 64 B = 4 groups of 16 B. Swizzle spreads staging stores
// (c>>2 ~ lane) and frag reads (c = base+ml) across groups: <=2-way, free.
static __device__ __forceinline__ int s2(int c) {
    return ((c >> 2) ^ ((c & 1) << 1)) & 3;
}

__global__ __launch_bounds__(256, 2) void hclt_gemm(
    const int* __restrict__ x, const float* __restrict__ W,
    const float* __restrict__ wsum, float* __restrict__ P)
{
    // staging: As 8 KB (128 c0 rows) | Bs 16 KB (256 c1 rows); epilogue reuses
    // the same memory as G[64][130] floats (33280 B).
    __shared__ __align__(16) char smem[33280];
    __shared__ int pairs[1024];

    char*  const As = smem;
    char*  const Bs = smem + 8192;
    float* const G  = (float*)smem;

    const int blk   = blockIdx.x;
    const int split = ((blk >> 4) << 3) | (blk & 7);   // blk and blk^8 share split+XCD
    const int h     = (blk >> 3) & 1;                  // c0 half
    const long kbase = (long)split * KCHUNK;

    const float* __restrict__ Ag = W + kbase * 256 + h * 128;   // W0 rows, col-half
    const float* __restrict__ Bg = W + 16777216 + kbase * 256;  // W1 rows

    const int t    = threadIdx.x;
    const int lane = t & 63;
    const int wv   = t >> 6;              // wave 0..3

    // observed pairs -> LDS (epilogue only)
#pragma unroll
    for (int jj = 0; jj < 4; ++jj) {
        const int2 p = ((const int2*)x)[t + 256 * jj];
        pairs[t + 256 * jj] = (p.x << 8) | p.y;
    }

    // staging geometry
    const bool isA = (t < 128);
    const int  uA  = t;                    // A: 32 c-quads x 4 k-octets
    const int  cqA = (uA & 31) * 4;
    const int  oA  = uA >> 5;              // octet 0..3
    const int  vB  = t & 127;              // B: 64 c-quads x (2 octets each)
    const int  cqB = (vB & 63) * 4;
    const int  oB  = (vB >> 6) * 2;        // octets {oB, oB+1}

    // compute geometry: wave tile 64(c0) x 128(c1)
    const int wc0 = (wv & 1) * 64;
    const int wc1 = (wv >> 1) * 128;
    const int ml  = lane & 15;
    const int qd  = lane >> 4;

    f32x4 acc[4][8];
#pragma unroll
    for (int i = 0; i < 4; ++i)
#pragma unroll
        for (int j = 0; j < 8; ++j) acc[i][j] = (f32x4){0.f, 0.f, 0.f, 0.f};

    float4 pf[16];   // A path uses [0..7], B path [0..15]

    // ---- prologue: load + stage iter 0 ----
    if (isA) {
#pragma unroll
        for (int r = 0; r < 8; ++r)
            pf[r] = *(const float4*)(Ag + (long)(oA * 8 + r) * 256 + cqA);
    } else {
#pragma unroll
        for (int uo = 0; uo < 2; ++uo)
#pragma unroll
            for (int r = 0; r < 8; ++r)
                pf[uo * 8 + r] = *(const float4*)(Bg + (long)((oB + uo) * 8 + r) * 256 + cqB);
    }
    if (isA) {
#pragma unroll
        for (int j = 0; j < 4; ++j) {
            const int c = cqA + j;
            bf16x8 av;
#pragma unroll
            for (int r = 0; r < 8; ++r) av[r] = f2bf(((const float*)&pf[r])[j]);
            *(bf16x8*)(As + c * 64 + ((oA ^ s2(c)) & 3) * 16) = av;
        }
    } else {
#pragma unroll
        for (int uo = 0; uo < 2; ++uo)
#pragma unroll
            for (int j = 0; j < 4; ++j) {
                const int c = cqB + j;
                bf16x8 bv;
#pragma unroll
                for (int r = 0; r < 8; ++r) bv[r] = f2bf(((const float*)&pf[uo * 8 + r])[j]);
                *(bf16x8*)(Bs + c * 64 + (((oB + uo) ^ s2(c)) & 3) * 16) = bv;
            }
    }
    __syncthreads();

    // ---- main loop: BK=32 (one MFMA k-step), prefetch iter+1 ----
#pragma unroll
    for (int it = 0; it < NITER; ++it) {
        if (it + 1 < NITER) {
            const long k0 = (long)(it + 1) * BK;
            if (isA) {
#pragma unroll
                for (int r = 0; r < 8; ++r)
                    pf[r] = *(const float4*)(Ag + (k0 + oA * 8 + r) * 256 + cqA);
            } else {
#pragma unroll
                for (int uo = 0; uo < 2; ++uo)
#pragma unroll
                    for (int r = 0; r < 8; ++r)
                        pf[uo * 8 + r] =
                            *(const float4*)(Bg + (k0 + (oB + uo) * 8 + r) * 256 + cqB);
            }
        }
        // compute from LDS
        bf16x8 afr[4];
#pragma unroll
        for (int mi = 0; mi < 4; ++mi) {
            const int c = wc0 + mi * 16 + ml;
            afr[mi] = *(const bf16x8*)(As + c * 64 + ((qd ^ s2(c)) & 3) * 16);
        }
#pragma unroll
        for (int ni = 0; ni < 8; ++ni) {
            const int c = wc1 + ni * 16 + ml;
            const bf16x8 bfr = *(const bf16x8*)(Bs + c * 64 + ((qd ^ s2(c)) & 3) * 16);
#pragma unroll
            for (int mi = 0; mi < 4; ++mi)
                acc[mi][ni] = __builtin_amdgcn_mfma_f32_16x16x32_bf16(
                    afr[mi], bfr, acc[mi][ni], 0, 0, 0);
        }
        if (it + 1 < NITER) {
            __syncthreads();               // done reading LDS
            if (isA) {
#pragma unroll
                for (int j = 0; j < 4; ++j) {
                    const int c = cqA + j;
                    bf16x8 av;
#pragma unroll
                    for (int r = 0; r < 8; ++r) av[r] = f2bf(((const float*)&pf[r])[j]);
                    *(bf16x8*)(As + c * 64 + ((oA ^ s2(c)) & 3) * 16) = av;
                }
            } else {
#pragma unroll
                for (int uo = 0; uo < 2; ++uo)
#pragma unroll
                    for (int j = 0; j < 4; ++j) {
                        const int c = cqB + j;
                        bf16x8 bv;
#pragma unroll
                        for (int r = 0; r < 8; ++r)
                            bv[r] = f2bf(((const float*)&pf[uo * 8 + r])[j]);
                        *(bf16x8*)(Bs + c * 64 + (((oB + uo) ^ s2(c)) & 3) * 16) = bv;
                    }
            }
            __syncthreads();
        }
    }

    // ---- epilogue: 4 phases, wave ph dumps its 64x128 tile, all gather ----
    // C/D layout: local c0 = mi*16 + qd*4 + r, local c1 = ni*16 + ml
    const float wk = wsum[split];
    float pv0 = 0.f, pv1 = 0.f, pv2 = 0.f, pv3 = 0.f;
#pragma unroll 1
    for (int ph = 0; ph < 4; ++ph) {
        __syncthreads();
        if (wv == ph) {
#pragma unroll
            for (int mi = 0; mi < 4; ++mi)
#pragma unroll
                for (int ni = 0; ni < 8; ++ni)
#pragma unroll
                    for (int r = 0; r < 4; ++r)
                        G[(mi * 16 + qd * 4 + r) * 130 + (ni * 16 + ml)] = acc[mi][ni][r];
        }
        __syncthreads();
#pragma unroll
        for (int jj = 0; jj < 4; ++jj) {
            const int pr = pairs[t + 256 * jj];
            const int c0 = pr >> 8, c1 = pr & 255;
            if ((c0 >> 7) == h && ((((c0 >> 6) & 1) | ((c1 >> 7) << 1)) == ph)) {
                const float v = G[(c0 & 63) * 130 + (c1 & 127)];
                if (jj == 0) pv0 = v; else if (jj == 1) pv1 = v;
                else if (jj == 2) pv2 = v; else pv3 = v;
            }
        }
    }
    float* __restrict__ Pb = P + (size_t)blk * 1024;
    Pb[t]       = pv0 * wk;               // coalesced, no atomics
    Pb[t + 256] = pv1 * wk;
    Pb[t + 512] = pv2 * wk;
    Pb[t + 768] = pv3 * wk;
}

// Reduce 512 per-block partials per output + log. 16 blocks x 256 threads;
// block handles 64 outputs, 4 threads each (s-quarters), LDS combine.
__global__ __launch_bounds__(256) void hclt_finish(
    const float* __restrict__ P, float* __restrict__ out)
{
    __shared__ float red[4][64];
    const int l = threadIdx.x & 63;
    const int q = threadIdx.x >> 6;
    const int i = blockIdx.x * 64 + l;
    float s = 0.f;
#pragma unroll 8
    for (int m = 0; m < 128; ++m)
        s += P[(size_t)(q + 4 * m) * 1024 + i];
    red[q][l] = s;
    __syncthreads();
    if (q == 0)
        out[i] = logf((red[0][l] + red[1][l]) + (red[2][l] + red[3][l]));
}

extern "C" void kernel_launch(void* const* d_in, const int* in_sizes, int n_in,
                              void* d_out, int out_size, void* d_ws, size_t ws_size,
                              hipStream_t stream)
{
    const int*   x    = (const int*)d_in[0];     // [1024,2] int32
    const float* W    = (const float*)d_in[1];   // [2,256,256,256] fp32
    const float* wsum = (const float*)d_in[2];   // [256] fp32
    float* out = (float*)d_out;                  // [1024] fp32

    float* P = (float*)d_ws;                     // 512 x 1024 floats = 2 MB

    hclt_gemm<<<dim3(512), 256, 0, stream>>>(x, W, wsum, P);
    hclt_finish<<<dim3(16), 256, 0, stream>>>(P, out);
}